// Round 14
// baseline (128.780 us; speedup 1.0000x reference)
//
#include <hip/hip_runtime.h>
#include <hip/hip_bf16.h>
#include <stdint.h>

// Problem constants: B=2, T=2048, C=1024, H=16, D=64
#define TT 2048
#define CC 1024
#define NH 16
#define HD 64
#define BT 4096          // B*T rows

typedef float f32x4 __attribute__((ext_vector_type(4)));
typedef __bf16 bf16x8 __attribute__((ext_vector_type(8)));
typedef __bf16 bf16x4 __attribute__((ext_vector_type(4)));
typedef short sh4 __attribute__((ext_vector_type(4)));

#define MFMA(a, b, c) __builtin_amdgcn_mfma_f32_16x16x32_bf16((a), (b), (c), 0, 0, 0)
#define MFMA16(a, b, c) __builtin_amdgcn_mfma_f32_16x16x16bf16_1k((a), (b), (c), 0, 0, 0)

__device__ __forceinline__ void gload16(const void* g, void* l) {
    __builtin_amdgcn_global_load_lds(
        (const __attribute__((address_space(1))) void*)g,
        (__attribute__((address_space(3))) void*)l,
        16, 0, 0);
}

// ------- fused prep: x fp32->bf16 convert + both weight transposes -------
__global__ __launch_bounds__(256) void prep(
    const float* __restrict__ x, __bf16* __restrict__ xb,
    const float* __restrict__ wa, __bf16* __restrict__ oa,
    const float* __restrict__ wp, __bf16* __restrict__ op) {
    __shared__ float tile[32][33];
    int b0 = blockIdx.x;
    if (b0 < 1024) {
        // conv: x [BT*CC] fp32 -> bf16
        int i = b0 * 256 + threadIdx.x;
        const int stride = 1024 * 256;
        const int n4 = BT * CC / 4;
        for (; i < n4; i += stride) {
            float4 v = reinterpret_cast<const float4*>(x)[i];
            bf16x4 o;
            o.x = (__bf16)v.x; o.y = (__bf16)v.y;
            o.z = (__bf16)v.z; o.w = (__bf16)v.w;
            reinterpret_cast<bf16x4*>(xb)[i] = o;
        }
    } else {
        // transpose: w_attn [1024][3072] / w_proj [1024][1024] -> bf16 [C][1024]
        int idx = b0 - 1024;
        int bx = idx & 127, r0 = (idx >> 7) * 32;
        const float* in;
        __bf16* out;
        int C;
        if (bx < 96) { in = wa; out = oa; C = 3072; }
        else         { in = wp; out = op; C = 1024; bx -= 96; }
        int c0 = bx * 32;
        int tx = threadIdx.x & 31, ty = (threadIdx.x >> 5) & 7;
#pragma unroll
        for (int j = 0; j < 32; j += 8)
            tile[ty + j][tx] = in[(size_t)(r0 + ty + j) * C + c0 + tx];
        __syncthreads();
#pragma unroll
        for (int j = 0; j < 32; j += 8)
            out[(size_t)(c0 + ty + j) * 1024 + r0 + tx] = (__bf16)tile[tx][ty + j];
    }
}

// ---------------- bf16 MFMA GEMM, 128x128 tile, BK=64 (m97 structure) ----
// C = A[M,K] * Bt[N,K]^T + bias. MODE 0: scatter q/k -> [B,H,T,D] bf16
// (q scaled by 0.125*log2e for exp2-softmax); v -> [B,H,D,T] bf16 with the
// attention V-swizzle PRE-BAKED per 128B (64-kv) group: within-group byte
// offset (t&63)*2 is XOR'd with (d&15)<<3, so attn stages it LINEARLY and
// reads b64 conflict-free [verified r10/r11: conflicts=0]. MODE 1: fp32 out.
template <int MODE>
__global__ __launch_bounds__(256) void gemm128(
    const __bf16* __restrict__ A, const __bf16* __restrict__ Bt,
    const float* __restrict__ bias,
    __bf16* __restrict__ oq, __bf16* __restrict__ ok, __bf16* __restrict__ ov,
    float* __restrict__ of, int M, int N, int K) {
    __shared__ __align__(16) __bf16 As[128 * 64];
    __shared__ __align__(16) __bf16 Bs[128 * 64];
    const int tid = threadIdx.x;
    const int w = tid >> 6, lane = tid & 63;
    const int l15 = lane & 15, lg = lane >> 4;
    const int m0 = blockIdx.y * 128, n0 = blockIdx.x * 128;
    const int wr = w >> 1, wc = w & 1;

    const f32x4 zero4 = {0.f, 0.f, 0.f, 0.f};
    f32x4 acc[4][4];
#pragma unroll
    for (int m = 0; m < 4; ++m)
#pragma unroll
        for (int n = 0; n < 4; ++n) acc[m][n] = zero4;

    const char* Ab = (const char*)A;
    const char* Bb = (const char*)Bt;
    const size_t rowbytes = (size_t)K * 2;

    for (int kt = 0; kt < K; kt += 64) {
#pragma unroll
        for (int j = 0; j < 4; ++j) {
            int base = (w * 4 + j) * 1024;
            int d0 = base + lane * 16;
            int row = d0 >> 7;
            int colb = d0 & 127;
            int scolb = colb ^ ((row & 7) << 4);
            gload16(Ab + (size_t)(m0 + row) * rowbytes + (size_t)kt * 2 + scolb,
                    (char*)As + base);
            gload16(Bb + (size_t)(n0 + row) * rowbytes + (size_t)kt * 2 + scolb,
                    (char*)Bs + base);
        }
        __syncthreads();
#pragma unroll
        for (int kk = 0; kk < 2; ++kk) {
            bf16x8 af[4], bfr[4];
#pragma unroll
            for (int m = 0; m < 4; ++m) {
                int row = wr * 64 + m * 16 + l15;
                int colb = kk * 64 + lg * 16;
                af[m] = *(const bf16x8*)((const char*)As + row * 128 +
                                         (colb ^ ((row & 7) << 4)));
            }
#pragma unroll
            for (int n = 0; n < 4; ++n) {
                int row = wc * 64 + n * 16 + l15;
                int colb = kk * 64 + lg * 16;
                bfr[n] = *(const bf16x8*)((const char*)Bs + row * 128 +
                                          (colb ^ ((row & 7) << 4)));
            }
#pragma unroll
            for (int m = 0; m < 4; ++m)
#pragma unroll
                for (int n = 0; n < 4; ++n)
                    acc[m][n] = MFMA(af[m], bfr[n], acc[m][n]);
        }
        __syncthreads();
    }

    // epilogue. D layout: col = lane&15, row = (lane>>4)*4 + r  [verified m89/m91]
#pragma unroll
    for (int n = 0; n < 4; ++n) {
        int col = n0 + wc * 64 + n * 16 + l15;
        float bs = bias[col];
        if constexpr (MODE == 0) {
            int sec = col >> 10;          // 0=q 1=k 2=v
            int cc = col & 1023;
            int h = cc >> 6, d = cc & 63;
            if (sec == 2) {
                // V transposed + swizzled: [B,H,D,T], byte addr =
                // base + (t&~63)*2 + ((t&63)*2 ^ ((d&15)<<3)); t 4-aligned
#pragma unroll
                for (int m = 0; m < 4; ++m) {
                    int rowb = m0 + wr * 64 + m * 16 + lg * 4;
                    int bb = rowb >> 11, t = rowb & 2047;
                    bf16x4 pk;
#pragma unroll
                    for (int r = 0; r < 4; ++r) pk[r] = (__bf16)(acc[m][n][r] + bs);
                    size_t base = ((size_t)(bb * NH + h) * HD + d) * (TT * 2);
                    size_t byte = base + (size_t)((t & ~63) * 2 +
                                   (((t & 63) * 2) ^ ((d & 15) << 3)));
                    *(bf16x4*)((char*)ov + byte) = pk;
                }
            } else {
                __bf16* dst = (sec == 0) ? oq : ok;
                // fold softmax scale AND log2(e) into q so attn uses exp2
                float mult = (sec == 0) ? 0.125f * 1.44269504088896340736f : 1.0f;
#pragma unroll
                for (int m = 0; m < 4; ++m) {
                    int rowb = m0 + wr * 64 + m * 16 + lg * 4;
#pragma unroll
                    for (int r = 0; r < 4; ++r) {
                        int row = rowb + r;
                        int bb = row >> 11, t = row & 2047;
                        float val = (acc[m][n][r] + bs) * mult;
                        dst[((size_t)(bb * NH + h) * TT + t) * HD + d] = (__bf16)val;
                    }
                }
            }
        } else {
#pragma unroll
            for (int m = 0; m < 4; ++m) {
                int rowb = m0 + wr * 64 + m * 16 + lg * 4;
#pragma unroll
                for (int r = 0; r < 4; ++r) {
                    int row = rowb + r;
                    of[(size_t)row * N + col] = acc[m][n][r] + bs;
                }
            }
        }
    }
}

// ---------------- causal flash attention (QTILE=128, 32 rows/wave) -------
// 512 blocks, 4 waves each; every wave owns TWO 16-row fragments (rows +0
// and +64 of the block's 128-row q-tile), so each K/V fragment read from
// LDS feeds 2 MFMAs: LDS traffic and fixed per-step cost per q-row halve
// vs r13. Pairing j<8->15-j / j>=8->j-8: co-resident block pairs (n, n+256)
// sum to exactly 36 steps. Static softmax (r13): no max/rescale; masked
// s=-1e30 -> exp2 -> 0 exactly (auto-handles frag0's dead tail tile).
// P register-resident (MFMA16); V b64 reads conflict-free via producer-baked
// (d&15)<<3 swizzle. LDS = 32KB.
// q,k: [B,H,T,64] bf16 (q pre-scaled by 0.125*log2e). vt: swizzled [B,H,64,T].
__global__ __launch_bounds__(256) void attn_kernel(
    const __bf16* __restrict__ q, const __bf16* __restrict__ k,
    const __bf16* __restrict__ vt, __bf16* __restrict__ y) {
    __shared__ __align__(16) __bf16 Kb[2][64 * 64];   // [kv][d] 128B rows, XOR swz
    __shared__ __align__(16) __bf16 Vb[2][64 * 64];   // [d][kv-swz] 128B rows

    const int n = blockIdx.x;
    const int j = n >> 5;                          // 0..15
    const int qt2 = (j < 8) ? 15 - j : j - 8;      // heavy first; pairs sum 36
    const int bh = ((n & 7) << 2) | ((n >> 3) & 3);  // 4 heads per XCD slot
    const int tid = threadIdx.x, w = tid >> 6, lane = tid & 63;
    const int l15 = lane & 15, lg = lane >> 4;
    const char* kh = (const char*)(k + (size_t)bh * TT * HD);
    const char* vh = (const char*)(vt + (size_t)bh * HD * TT);
    const __bf16* qh = q + (size_t)bh * TT * HD;
    const int qbw[2] = { qt2 * 128 + w * 16, qt2 * 128 + 64 + w * 16 };
    const int nt = 2 * qt2 + 2;                    // 64-wide KV tiles

    const f32x4 zero4 = {0.f, 0.f, 0.f, 0.f};
    float lrun[2] = {0.f, 0.f};        // per-lane partials (16 k each)
    f32x4 oacc[2][4];                  // O^T: col=q=l15, row d = f*16+lg*4+r
    bf16x8 qf[2][2];
#pragma unroll
    for (int a = 0; a < 2; ++a) {
#pragma unroll
        for (int f = 0; f < 4; ++f) oacc[a][f] = zero4;
#pragma unroll
        for (int kk = 0; kk < 2; ++kk)
            qf[a][kk] = *(const bf16x8*)&qh[(size_t)(qbw[a] + l15) * HD +
                                           kk * 32 + lg * 8];
    }

    auto stage = [&](int kvb, int buf) {
#pragma unroll
        for (int jj = 0; jj < 2; ++jj) {
            int d0 = ((w * 2 + jj) * 64 + lane) * 16;
            int row = d0 >> 7, colb = d0 & 127;
            // K: source-XOR swizzle; V: linear (swizzle baked in global layout)
            gload16(kh + (size_t)(kvb + row) * 128 + (colb ^ ((row & 7) << 4)),
                    (char*)Kb[buf] + d0);
            gload16(vh + (size_t)row * (TT * 2) + (size_t)kvb * 2 + colb,
                    (char*)Vb[buf] + d0);
        }
    };

    stage(0, 0);
    __syncthreads();

    for (int g = 0; g < nt; ++g) {
        const int cur = g & 1;
        if (g + 1 < nt) stage((g + 1) * 64, cur ^ 1);
        const int kb = g * 64;

        // ---- S^T = K Q^T, both fragments share k0/k1 reads ----
        f32x4 s[2][4];
#pragma unroll
        for (int a = 0; a < 2; ++a)
#pragma unroll
            for (int kf = 0; kf < 4; ++kf) s[a][kf] = zero4;
        __builtin_amdgcn_s_setprio(1);
#pragma unroll
        for (int kf = 0; kf < 4; ++kf) {
            int krow = kf * 16 + l15;
            const char* kr = (const char*)Kb[cur] + krow * 128;
            bf16x8 k0 = *(const bf16x8*)(kr + ((lg * 16) ^ ((krow & 7) << 4)));
            bf16x8 k1 = *(const bf16x8*)(kr + ((64 + lg * 16) ^ ((krow & 7) << 4)));
            s[0][kf] = MFMA(k0, qf[0][0], s[0][kf]);
            s[0][kf] = MFMA(k1, qf[0][1], s[0][kf]);
            s[1][kf] = MFMA(k0, qf[1][0], s[1][kf]);
            s[1][kf] = MFMA(k1, qf[1][1], s[1][kf]);
        }
        __builtin_amdgcn_s_setprio(0);
        // ---- causal mask per fragment (past-diagonal tiles fully mask) ----
#pragma unroll
        for (int a = 0; a < 2; ++a) {
            if (kb + 63 > qbw[a]) {
                const int qq = qbw[a] + l15;
#pragma unroll
                for (int kf = 0; kf < 4; ++kf)
#pragma unroll
                    for (int r = 0; r < 4; ++r) {
                        int kk_ = kb + kf * 16 + lg * 4 + r;
                        if (kk_ > qq) s[a][kf][r] = -1e30f;
                    }
            }
        }
        // ---- static softmax: P = exp2(s) (masked -> 0 exactly) ----
        sh4 pb[2][4];
#pragma unroll
        for (int a = 0; a < 2; ++a) {
            float ss0 = 0.f, ss1 = 0.f;
#pragma unroll
            for (int kf = 0; kf < 4; ++kf) {
                bf16x4 pk;
#pragma unroll
                for (int r = 0; r < 4; ++r) {
                    float p = exp2f(s[a][kf][r]);
                    pk[r] = (__bf16)p;
                    if (kf & 1) ss1 += p; else ss0 += p;
                }
                pb[a][kf] = __builtin_bit_cast(sh4, pk);
            }
            lrun[a] += ss0 + ss1;
        }
        // ---- O^T += V^T P ---- 16x16x16; va shared by both fragments
        __builtin_amdgcn_s_setprio(1);
#pragma unroll
        for (int kf = 0; kf < 4; ++kf) {
            int cb = (kf * 32 + lg * 8) ^ (l15 << 3);
#pragma unroll
            for (int f = 0; f < 4; ++f) {
                int vrow = f * 16 + l15;
                bf16x4 va = *(const bf16x4*)((const char*)Vb[cur] + vrow * 128 + cb);
                sh4 vs = __builtin_bit_cast(sh4, va);
                oacc[0][f] = MFMA16(vs, pb[0][kf], oacc[0][f]);
                oacc[1][f] = MFMA16(vs, pb[1][kf], oacc[1][f]);
            }
        }
        __builtin_amdgcn_s_setprio(0);
        __syncthreads();
    }

    // epilogue: finish lrun reduction across the 4 lg groups, write O^T
    const int b = bh >> 4, h = bh & 15;
#pragma unroll
    for (int a = 0; a < 2; ++a) {
        float lr = lrun[a];
        lr += __shfl_xor(lr, 16);
        lr += __shfl_xor(lr, 32);
        float inv = 1.0f / lr;
#pragma unroll
        for (int f = 0; f < 4; ++f) {
            bf16x4 pk;
#pragma unroll
            for (int r = 0; r < 4; ++r) pk[r] = (__bf16)(oacc[a][f][r] * inv);
            *(bf16x4*)&y[(size_t)(b * TT + qbw[a] + l15) * CC + h * 64 + f * 16 +
                         lg * 4] = pk;
        }
    }
}

extern "C" void kernel_launch(void* const* d_in, const int* in_sizes, int n_in,
                              void* d_out, int out_size, void* d_ws, size_t ws_size,
                              hipStream_t stream) {
    const float* x      = (const float*)d_in[0];
    const float* w_attn = (const float*)d_in[1];
    const float* b_attn = (const float*)d_in[2];
    const float* w_proj = (const float*)d_in[3];
    const float* b_proj = (const float*)d_in[4];
    float* out = (float*)d_out;

    char* ws = (char*)d_ws;
    size_t off = 0;
    auto alloc = [&](size_t bytes) {
        char* p = ws + off;
        off += (bytes + 255) & ~(size_t)255;
        return p;
    };
    __bf16* xb   = (__bf16*)alloc((size_t)BT * CC * 2);
    __bf16* watb = (__bf16*)alloc((size_t)3 * CC * CC * 2);
    __bf16* wptb = (__bf16*)alloc((size_t)CC * CC * 2);
    __bf16* qb   = (__bf16*)alloc((size_t)BT * CC * 2);
    __bf16* kbuf = (__bf16*)alloc((size_t)BT * CC * 2);
    __bf16* vtb  = (__bf16*)alloc((size_t)BT * CC * 2);  // [B,H,D,T] swizzled
    __bf16* yb   = (__bf16*)alloc((size_t)BT * CC * 2);

    prep<<<5120, 256, 0, stream>>>(x, xb, w_attn, watb, w_proj, wptb);

    gemm128<0><<<dim3(3 * CC / 128, BT / 128), 256, 0, stream>>>(
        xb, watb, b_attn, qb, kbuf, vtb, nullptr, BT, 3 * CC, CC);

    attn_kernel<<<512, 256, 0, stream>>>(qb, kbuf, vtb, yb);

    gemm128<1><<<dim3(CC / 128, BT / 128), 256, 0, stream>>>(
        yb, wptb, b_proj, nullptr, nullptr, nullptr, out, BT, CC, CC);
}

// Round 15
// 109.780 us; speedup vs baseline: 1.1731x; 1.1731x over previous
//
#include <hip/hip_runtime.h>
#include <hip/hip_bf16.h>
#include <stdint.h>

// Problem constants: B=2, T=2048, C=1024, H=16, D=64
#define TT 2048
#define CC 1024
#define NH 16
#define HD 64
#define BT 4096          // B*T rows

typedef float f32x4 __attribute__((ext_vector_type(4)));
typedef __bf16 bf16x8 __attribute__((ext_vector_type(8)));
typedef __bf16 bf16x4 __attribute__((ext_vector_type(4)));
typedef short sh4 __attribute__((ext_vector_type(4)));

#define MFMA(a, b, c) __builtin_amdgcn_mfma_f32_16x16x32_bf16((a), (b), (c), 0, 0, 0)
#define MFMA16(a, b, c) __builtin_amdgcn_mfma_f32_16x16x16bf16_1k((a), (b), (c), 0, 0, 0)

__device__ __forceinline__ void gload16(const void* g, void* l) {
    __builtin_amdgcn_global_load_lds(
        (const __attribute__((address_space(1))) void*)g,
        (__attribute__((address_space(3))) void*)l,
        16, 0, 0);
}

// ------- fused prep: x fp32->bf16 convert + both weight transposes -------
__global__ __launch_bounds__(256) void prep(
    const float* __restrict__ x, __bf16* __restrict__ xb,
    const float* __restrict__ wa, __bf16* __restrict__ oa,
    const float* __restrict__ wp, __bf16* __restrict__ op) {
    __shared__ float tile[32][33];
    int b0 = blockIdx.x;
    if (b0 < 1024) {
        // conv: x [BT*CC] fp32 -> bf16
        int i = b0 * 256 + threadIdx.x;
        const int stride = 1024 * 256;
        const int n4 = BT * CC / 4;
        for (; i < n4; i += stride) {
            float4 v = reinterpret_cast<const float4*>(x)[i];
            bf16x4 o;
            o.x = (__bf16)v.x; o.y = (__bf16)v.y;
            o.z = (__bf16)v.z; o.w = (__bf16)v.w;
            reinterpret_cast<bf16x4*>(xb)[i] = o;
        }
    } else {
        // transpose: w_attn [1024][3072] / w_proj [1024][1024] -> bf16 [C][1024]
        int idx = b0 - 1024;
        int bx = idx & 127, r0 = (idx >> 7) * 32;
        const float* in;
        __bf16* out;
        int C;
        if (bx < 96) { in = wa; out = oa; C = 3072; }
        else         { in = wp; out = op; C = 1024; bx -= 96; }
        int c0 = bx * 32;
        int tx = threadIdx.x & 31, ty = (threadIdx.x >> 5) & 7;
#pragma unroll
        for (int j = 0; j < 32; j += 8)
            tile[ty + j][tx] = in[(size_t)(r0 + ty + j) * C + c0 + tx];
        __syncthreads();
#pragma unroll
        for (int j = 0; j < 32; j += 8)
            out[(size_t)(c0 + ty + j) * 1024 + r0 + tx] = (__bf16)tile[tx][ty + j];
    }
}

// ---------------- bf16 MFMA GEMM, 128x128 tile, BK=64 (m97 structure) ----
// C = A[M,K] * Bt[N,K]^T + bias. MODE 0: scatter q/k -> [B,H,T,D] bf16
// (q scaled by 0.125*log2e for exp2-softmax); v -> [B,H,D,T] bf16 with the
// attention V-swizzle PRE-BAKED per 128B (64-kv) group: within-group byte
// offset (t&63)*2 is XOR'd with (d&15)<<3, so attn stages it LINEARLY and
// reads b64 conflict-free [verified r10/r11: conflicts=0]. MODE 1: fp32 out.
template <int MODE>
__global__ __launch_bounds__(256) void gemm128(
    const __bf16* __restrict__ A, const __bf16* __restrict__ Bt,
    const float* __restrict__ bias,
    __bf16* __restrict__ oq, __bf16* __restrict__ ok, __bf16* __restrict__ ov,
    float* __restrict__ of, int M, int N, int K) {
    __shared__ __align__(16) __bf16 As[128 * 64];
    __shared__ __align__(16) __bf16 Bs[128 * 64];
    const int tid = threadIdx.x;
    const int w = tid >> 6, lane = tid & 63;
    const int l15 = lane & 15, lg = lane >> 4;
    const int m0 = blockIdx.y * 128, n0 = blockIdx.x * 128;
    const int wr = w >> 1, wc = w & 1;

    const f32x4 zero4 = {0.f, 0.f, 0.f, 0.f};
    f32x4 acc[4][4];
#pragma unroll
    for (int m = 0; m < 4; ++m)
#pragma unroll
        for (int n = 0; n < 4; ++n) acc[m][n] = zero4;

    const char* Ab = (const char*)A;
    const char* Bb = (const char*)Bt;
    const size_t rowbytes = (size_t)K * 2;

    for (int kt = 0; kt < K; kt += 64) {
#pragma unroll
        for (int j = 0; j < 4; ++j) {
            int base = (w * 4 + j) * 1024;
            int d0 = base + lane * 16;
            int row = d0 >> 7;
            int colb = d0 & 127;
            int scolb = colb ^ ((row & 7) << 4);
            gload16(Ab + (size_t)(m0 + row) * rowbytes + (size_t)kt * 2 + scolb,
                    (char*)As + base);
            gload16(Bb + (size_t)(n0 + row) * rowbytes + (size_t)kt * 2 + scolb,
                    (char*)Bs + base);
        }
        __syncthreads();
#pragma unroll
        for (int kk = 0; kk < 2; ++kk) {
            bf16x8 af[4], bfr[4];
#pragma unroll
            for (int m = 0; m < 4; ++m) {
                int row = wr * 64 + m * 16 + l15;
                int colb = kk * 64 + lg * 16;
                af[m] = *(const bf16x8*)((const char*)As + row * 128 +
                                         (colb ^ ((row & 7) << 4)));
            }
#pragma unroll
            for (int n = 0; n < 4; ++n) {
                int row = wc * 64 + n * 16 + l15;
                int colb = kk * 64 + lg * 16;
                bfr[n] = *(const bf16x8*)((const char*)Bs + row * 128 +
                                          (colb ^ ((row & 7) << 4)));
            }
#pragma unroll
            for (int m = 0; m < 4; ++m)
#pragma unroll
                for (int n = 0; n < 4; ++n)
                    acc[m][n] = MFMA(af[m], bfr[n], acc[m][n]);
        }
        __syncthreads();
    }

    // epilogue. D layout: col = lane&15, row = (lane>>4)*4 + r  [verified m89/m91]
#pragma unroll
    for (int n = 0; n < 4; ++n) {
        int col = n0 + wc * 64 + n * 16 + l15;
        float bs = bias[col];
        if constexpr (MODE == 0) {
            int sec = col >> 10;          // 0=q 1=k 2=v
            int cc = col & 1023;
            int h = cc >> 6, d = cc & 63;
            if (sec == 2) {
                // V transposed + swizzled: [B,H,D,T], byte addr =
                // base + (t&~63)*2 + ((t&63)*2 ^ ((d&15)<<3)); t 4-aligned
#pragma unroll
                for (int m = 0; m < 4; ++m) {
                    int rowb = m0 + wr * 64 + m * 16 + lg * 4;
                    int bb = rowb >> 11, t = rowb & 2047;
                    bf16x4 pk;
#pragma unroll
                    for (int r = 0; r < 4; ++r) pk[r] = (__bf16)(acc[m][n][r] + bs);
                    size_t base = ((size_t)(bb * NH + h) * HD + d) * (TT * 2);
                    size_t byte = base + (size_t)((t & ~63) * 2 +
                                   (((t & 63) * 2) ^ ((d & 15) << 3)));
                    *(bf16x4*)((char*)ov + byte) = pk;
                }
            } else {
                __bf16* dst = (sec == 0) ? oq : ok;
                // fold softmax scale AND log2(e) into q so attn uses exp2
                float mult = (sec == 0) ? 0.125f * 1.44269504088896340736f : 1.0f;
#pragma unroll
                for (int m = 0; m < 4; ++m) {
                    int rowb = m0 + wr * 64 + m * 16 + lg * 4;
#pragma unroll
                    for (int r = 0; r < 4; ++r) {
                        int row = rowb + r;
                        int bb = row >> 11, t = row & 2047;
                        float val = (acc[m][n][r] + bs) * mult;
                        dst[((size_t)(bb * NH + h) * TT + t) * HD + d] = (__bf16)val;
                    }
                }
            }
        } else {
#pragma unroll
            for (int m = 0; m < 4; ++m) {
                int rowb = m0 + wr * 64 + m * 16 + lg * 4;
#pragma unroll
                for (int r = 0; r < 4; ++r) {
                    int row = rowb + r;
                    of[(size_t)row * N + col] = acc[m][n][r] + bs;
                }
            }
        }
    }
}

// ---------------- causal flash attention (r13 body + heavy-tile KV split)
// Static softmax (no max shift) makes partials DIRECTLY ADDITIVE:
// O = O0+O1, l = l0+l1. Heavy q-tiles (qt>=16) are computed by 2 blocks
// covering KV halves (<=16 steps each) that write unnormalized bf16 O-partials
// + fp32 l-partials; light tiles (qt<=15, <=16 steps) write y directly.
// Grid = 1536 uniform blocks (heavy halves dispatched first), 4 heads/XCD
// slot. Per-step body identical to r13 (swapped QK^T, reg-P MFMA16,
// producer-baked V swizzle, conflicts=0). LDS = 32KB -> 5 resident/CU.
__global__ __launch_bounds__(256) void attn_kernel(
    const __bf16* __restrict__ q, const __bf16* __restrict__ k,
    const __bf16* __restrict__ vt, __bf16* __restrict__ y,
    __bf16* __restrict__ opart, float* __restrict__ lpart) {
    __shared__ __align__(16) __bf16 Kb[2][64 * 64];   // [kv][d] 128B rows, XOR swz
    __shared__ __align__(16) __bf16 Vb[2][64 * 64];   // [d][kv-swz] 128B rows

    const int n = blockIdx.x;
    const int bh = ((n & 7) << 2) | ((n >> 3) & 3);  // 4 heads per XCD slot
    const int u = n >> 5;                            // 0..47
    int qt, g0, g1, half;
    const bool heavy = (u < 32);
    if (heavy) {
        qt = 16 + (u >> 1);
        half = u & 1;
        int n0 = (qt + 2) >> 1;                      // ceil((qt+1)/2) <= 16
        g0 = half ? n0 : 0;
        g1 = half ? qt + 1 : n0;
    } else {
        qt = 47 - u;                                 // 15 down to 0
        half = 0;
        g0 = 0;
        g1 = qt + 1;
    }
    const int tid = threadIdx.x, w = tid >> 6, lane = tid & 63;
    const int l15 = lane & 15, lg = lane >> 4;
    const char* kh = (const char*)(k + (size_t)bh * TT * HD);
    const char* vh = (const char*)(vt + (size_t)bh * HD * TT);
    const __bf16* qh = q + (size_t)bh * TT * HD;
    const int qbw = qt * 64 + w * 16;

    const f32x4 zero4 = {0.f, 0.f, 0.f, 0.f};
    float lrun = 0.f;                  // per-lane partial (16 k each)
    f32x4 oacc[4];                     // O^T: col=q=l15, row d = f*16+lg*4+r
    bf16x8 qf[2];
#pragma unroll
    for (int f = 0; f < 4; ++f) oacc[f] = zero4;
#pragma unroll
    for (int kk = 0; kk < 2; ++kk)
        qf[kk] = *(const bf16x8*)&qh[(size_t)(qbw + l15) * HD + kk * 32 + lg * 8];

    auto stage = [&](int kvb, int buf) {
#pragma unroll
        for (int j = 0; j < 2; ++j) {
            int d0 = ((w * 2 + j) * 64 + lane) * 16;
            int row = d0 >> 7, colb = d0 & 127;
            // K: source-XOR swizzle; V: linear (swizzle baked in global layout)
            gload16(kh + (size_t)(kvb + row) * 128 + (colb ^ ((row & 7) << 4)),
                    (char*)Kb[buf] + d0);
            gload16(vh + (size_t)row * (TT * 2) + (size_t)kvb * 2 + colb,
                    (char*)Vb[buf] + d0);
        }
    };

    stage(g0 * 64, 0);
    __syncthreads();

    for (int g = g0; g < g1; ++g) {
        const int cur = (g - g0) & 1;
        if (g + 1 < g1) stage((g + 1) * 64, cur ^ 1);
        const int kb = g * 64;

        // ---- S^T = K Q^T ---- (col=q=l15, row k = kf*16 + lg*4 + r)
        f32x4 s[4];
#pragma unroll
        for (int kf = 0; kf < 4; ++kf) s[kf] = zero4;
        __builtin_amdgcn_s_setprio(1);
#pragma unroll
        for (int kf = 0; kf < 4; ++kf) {
            int krow = kf * 16 + l15;
            const char* kr = (const char*)Kb[cur] + krow * 128;
            bf16x8 k0 = *(const bf16x8*)(kr + ((lg * 16) ^ ((krow & 7) << 4)));
            bf16x8 k1 = *(const bf16x8*)(kr + ((64 + lg * 16) ^ ((krow & 7) << 4)));
            s[kf] = MFMA(k0, qf[0], s[kf]);
            s[kf] = MFMA(k1, qf[1], s[kf]);
        }
        __builtin_amdgcn_s_setprio(0);
        // only the diagonal tile (g == qt) needs the causal mask
        if (g == qt) {
            const int qq = qbw + l15;
#pragma unroll
            for (int kf = 0; kf < 4; ++kf)
#pragma unroll
                for (int r = 0; r < 4; ++r) {
                    int kk_ = kb + kf * 16 + lg * 4 + r;
                    if (kk_ > qq) s[kf][r] = -1e30f;
                }
        }
        // ---- static softmax: P = exp2(s), no max shift, no rescale ----
        float ss = 0.f;
        sh4 pb[4];                         // P^T bf16, register-resident
#pragma unroll
        for (int kf = 0; kf < 4; ++kf) {
            bf16x4 pk;
#pragma unroll
            for (int r = 0; r < 4; ++r) {
                float p = exp2f(s[kf][r]);   // masked (-1e30) -> 0 exactly
                pk[r] = (__bf16)p;
                ss += p;
            }
            pb[kf] = __builtin_bit_cast(sh4, pk);
        }
        lrun += ss;                        // cross-lane sum deferred to epilogue
        // ---- O^T += V^T P ---- 16x16x16: A=V^T (k=lg*4+j via baked swizzle)
        __builtin_amdgcn_s_setprio(1);
#pragma unroll
        for (int kf = 0; kf < 4; ++kf) {
            int cb = (kf * 32 + lg * 8) ^ (l15 << 3);
#pragma unroll
            for (int f = 0; f < 4; ++f) {
                int vrow = f * 16 + l15;
                bf16x4 va = *(const bf16x4*)((const char*)Vb[cur] + vrow * 128 + cb);
                oacc[f] = MFMA16(__builtin_bit_cast(sh4, va), pb[kf], oacc[f]);
            }
        }
        __builtin_amdgcn_s_setprio(0);
        __syncthreads();
    }

    // epilogue: finish the lrun reduction across the 4 lg groups
    lrun += __shfl_xor(lrun, 16);
    lrun += __shfl_xor(lrun, 32);
    if (heavy) {
        // write UNNORMALIZED partials (bf16 O, fp32 l); combine() finishes
        size_t base = ((size_t)(bh * 16 + (qt - 16)) * 2 + half);
        __bf16* op = opart + base * 4096;
        float* lp = lpart + base * 64;
        if (lg == 0) lp[w * 16 + l15] = lrun;
#pragma unroll
        for (int f = 0; f < 4; ++f) {
            bf16x4 pk;
#pragma unroll
            for (int r = 0; r < 4; ++r) pk[r] = (__bf16)oacc[f][r];
            *(bf16x4*)&op[(size_t)(w * 16 + l15) * 64 + f * 16 + lg * 4] = pk;
        }
    } else {
        const int b = bh >> 4, h = bh & 15;
        float inv = 1.0f / lrun;
#pragma unroll
        for (int f = 0; f < 4; ++f) {
            bf16x4 pk;
#pragma unroll
            for (int r = 0; r < 4; ++r) pk[r] = (__bf16)(oacc[f][r] * inv);
            *(bf16x4*)&y[(size_t)(b * TT + qbw + l15) * CC + h * 64 + f * 16 +
                         lg * 4] = pk;
        }
    }
}

// ---------------- combine: y = (O0+O1)/(l0+l1) for heavy q-tiles ---------
__global__ __launch_bounds__(256) void combine(
    const __bf16* __restrict__ opart, const float* __restrict__ lpart,
    __bf16* __restrict__ y) {
    int n = blockIdx.x;                 // 512 = 32 bh x 16 qi
    int bh = n & 31, qi = n >> 5;
    int b = bh >> 4, h = bh & 15;
    int qt = 16 + qi;
    size_t base = ((size_t)(bh * 16 + qi)) * 2;
    const __bf16* o0 = opart + base * 4096;
    const __bf16* o1 = opart + (base + 1) * 4096;
    const float* l0 = lpart + base * 64;
    const float* l1 = l0 + 64;
    int t = threadIdx.x;
    int qq = t >> 2, dbase = (t & 3) * 16;
    float inv = 1.0f / (l0[qq] + l1[qq]);
    const __bf16* p0 = &o0[qq * 64 + dbase];
    const __bf16* p1 = &o1[qq * 64 + dbase];
    bf16x8 a0 = *(const bf16x8*)p0;
    bf16x8 a1 = *(const bf16x8*)(p0 + 8);
    bf16x8 c0 = *(const bf16x8*)p1;
    bf16x8 c1 = *(const bf16x8*)(p1 + 8);
    bf16x8 r0, r1;
#pragma unroll
    for (int i = 0; i < 8; ++i) {
        r0[i] = (__bf16)(((float)a0[i] + (float)c0[i]) * inv);
        r1[i] = (__bf16)(((float)a1[i] + (float)c1[i]) * inv);
    }
    __bf16* yp = &y[((size_t)(b * TT + qt * 64 + qq)) * CC + h * 64 + dbase];
    *(bf16x8*)yp = r0;
    *(bf16x8*)(yp + 8) = r1;
}

extern "C" void kernel_launch(void* const* d_in, const int* in_sizes, int n_in,
                              void* d_out, int out_size, void* d_ws, size_t ws_size,
                              hipStream_t stream) {
    const float* x      = (const float*)d_in[0];
    const float* w_attn = (const float*)d_in[1];
    const float* b_attn = (const float*)d_in[2];
    const float* w_proj = (const float*)d_in[3];
    const float* b_proj = (const float*)d_in[4];
    float* out = (float*)d_out;

    char* ws = (char*)d_ws;
    size_t off = 0;
    auto alloc = [&](size_t bytes) {
        char* p = ws + off;
        off += (bytes + 255) & ~(size_t)255;
        return p;
    };
    __bf16* xb   = (__bf16*)alloc((size_t)BT * CC * 2);      // 8MB
    __bf16* watb = (__bf16*)alloc((size_t)3 * CC * CC * 2);  // 6MB
    __bf16* wptb = (__bf16*)alloc((size_t)CC * CC * 2);
    __bf16* qb   = (__bf16*)alloc((size_t)BT * CC * 2);
    __bf16* kbuf = (__bf16*)alloc((size_t)BT * CC * 2);
    __bf16* vtb  = (__bf16*)alloc((size_t)BT * CC * 2);  // [B,H,D,T] swizzled
    __bf16* yb   = (__bf16*)alloc((size_t)BT * CC * 2);
    // partial buffers REUSE xb (opart: exactly 8MB) and watb (lpart: 256KB);
    // both are dead after gemm0, and attn runs after gemm0 (stream-ordered).
    __bf16* opart = xb;
    float*  lpart = (float*)watb;

    prep<<<5120, 256, 0, stream>>>(x, xb, w_attn, watb, w_proj, wptb);

    gemm128<0><<<dim3(3 * CC / 128, BT / 128), 256, 0, stream>>>(
        xb, watb, b_attn, qb, kbuf, vtb, nullptr, BT, 3 * CC, CC);

    attn_kernel<<<1536, 256, 0, stream>>>(qb, kbuf, vtb, yb, opart, lpart);

    combine<<<512, 256, 0, stream>>>(opart, lpart, yb);

    gemm128<1><<<dim3(CC / 128, BT / 128), 256, 0, stream>>>(
        yb, wptb, b_proj, nullptr, nullptr, nullptr, out, BT, CC, CC);
}

// Round 16
// 109.100 us; speedup vs baseline: 1.1804x; 1.0062x over previous
//
#include <hip/hip_runtime.h>
#include <hip/hip_bf16.h>
#include <stdint.h>

// Problem constants: B=2, T=2048, C=1024, H=16, D=64
#define TT 2048
#define CC 1024
#define NH 16
#define HD 64
#define BT 4096          // B*T rows

typedef float f32x4 __attribute__((ext_vector_type(4)));
typedef __bf16 bf16x8 __attribute__((ext_vector_type(8)));
typedef __bf16 bf16x4 __attribute__((ext_vector_type(4)));
typedef short sh4 __attribute__((ext_vector_type(4)));

#define MFMA(a, b, c) __builtin_amdgcn_mfma_f32_16x16x32_bf16((a), (b), (c), 0, 0, 0)
#define MFMA16(a, b, c) __builtin_amdgcn_mfma_f32_16x16x16bf16_1k((a), (b), (c), 0, 0, 0)

__device__ __forceinline__ void gload16(const void* g, void* l) {
    __builtin_amdgcn_global_load_lds(
        (const __attribute__((address_space(1))) void*)g,
        (__attribute__((address_space(3))) void*)l,
        16, 0, 0);
}

// ------- fused prep: x fp32->bf16 convert + both weight transposes -------
__global__ __launch_bounds__(256) void prep(
    const float* __restrict__ x, __bf16* __restrict__ xb,
    const float* __restrict__ wa, __bf16* __restrict__ oa,
    const float* __restrict__ wp, __bf16* __restrict__ op) {
    __shared__ float tile[32][33];
    int b0 = blockIdx.x;
    if (b0 < 1024) {
        // conv: x [BT*CC] fp32 -> bf16
        int i = b0 * 256 + threadIdx.x;
        const int stride = 1024 * 256;
        const int n4 = BT * CC / 4;
        for (; i < n4; i += stride) {
            float4 v = reinterpret_cast<const float4*>(x)[i];
            bf16x4 o;
            o.x = (__bf16)v.x; o.y = (__bf16)v.y;
            o.z = (__bf16)v.z; o.w = (__bf16)v.w;
            reinterpret_cast<bf16x4*>(xb)[i] = o;
        }
    } else {
        // transpose: w_attn [1024][3072] / w_proj [1024][1024] -> bf16 [C][1024]
        int idx = b0 - 1024;
        int bx = idx & 127, r0 = (idx >> 7) * 32;
        const float* in;
        __bf16* out;
        int C;
        if (bx < 96) { in = wa; out = oa; C = 3072; }
        else         { in = wp; out = op; C = 1024; bx -= 96; }
        int c0 = bx * 32;
        int tx = threadIdx.x & 31, ty = (threadIdx.x >> 5) & 7;
#pragma unroll
        for (int j = 0; j < 32; j += 8)
            tile[ty + j][tx] = in[(size_t)(r0 + ty + j) * C + c0 + tx];
        __syncthreads();
#pragma unroll
        for (int j = 0; j < 32; j += 8)
            out[(size_t)(c0 + ty + j) * 1024 + r0 + tx] = (__bf16)tile[tx][ty + j];
    }
}

// ---------------- bf16 MFMA GEMM, 128x128 tile, BK=64 (m97 structure) ----
// C = A[M,K] * Bt[N,K]^T + bias. MODE 0: scatter q/k -> [B,H,T,D] bf16
// (q scaled by 0.125*log2e for exp2-softmax); v -> [B,H,D,T] bf16 with the
// attention V-swizzle PRE-BAKED per 128B (64-kv) group: within-group byte
// offset (t&63)*2 is XOR'd with (d&15)<<3, so attn stages it LINEARLY and
// reads b64 conflict-free [verified r10/r11: conflicts=0]. MODE 1: fp32 out.
template <int MODE>
__global__ __launch_bounds__(256) void gemm128(
    const __bf16* __restrict__ A, const __bf16* __restrict__ Bt,
    const float* __restrict__ bias,
    __bf16* __restrict__ oq, __bf16* __restrict__ ok, __bf16* __restrict__ ov,
    float* __restrict__ of, int M, int N, int K) {
    __shared__ __align__(16) __bf16 As[128 * 64];
    __shared__ __align__(16) __bf16 Bs[128 * 64];
    const int tid = threadIdx.x;
    const int w = tid >> 6, lane = tid & 63;
    const int l15 = lane & 15, lg = lane >> 4;
    const int m0 = blockIdx.y * 128, n0 = blockIdx.x * 128;
    const int wr = w >> 1, wc = w & 1;

    const f32x4 zero4 = {0.f, 0.f, 0.f, 0.f};
    f32x4 acc[4][4];
#pragma unroll
    for (int m = 0; m < 4; ++m)
#pragma unroll
        for (int n = 0; n < 4; ++n) acc[m][n] = zero4;

    const char* Ab = (const char*)A;
    const char* Bb = (const char*)Bt;
    const size_t rowbytes = (size_t)K * 2;

    for (int kt = 0; kt < K; kt += 64) {
#pragma unroll
        for (int j = 0; j < 4; ++j) {
            int base = (w * 4 + j) * 1024;
            int d0 = base + lane * 16;
            int row = d0 >> 7;
            int colb = d0 & 127;
            int scolb = colb ^ ((row & 7) << 4);
            gload16(Ab + (size_t)(m0 + row) * rowbytes + (size_t)kt * 2 + scolb,
                    (char*)As + base);
            gload16(Bb + (size_t)(n0 + row) * rowbytes + (size_t)kt * 2 + scolb,
                    (char*)Bs + base);
        }
        __syncthreads();
#pragma unroll
        for (int kk = 0; kk < 2; ++kk) {
            bf16x8 af[4], bfr[4];
#pragma unroll
            for (int m = 0; m < 4; ++m) {
                int row = wr * 64 + m * 16 + l15;
                int colb = kk * 64 + lg * 16;
                af[m] = *(const bf16x8*)((const char*)As + row * 128 +
                                         (colb ^ ((row & 7) << 4)));
            }
#pragma unroll
            for (int n = 0; n < 4; ++n) {
                int row = wc * 64 + n * 16 + l15;
                int colb = kk * 64 + lg * 16;
                bfr[n] = *(const bf16x8*)((const char*)Bs + row * 128 +
                                          (colb ^ ((row & 7) << 4)));
            }
#pragma unroll
            for (int m = 0; m < 4; ++m)
#pragma unroll
                for (int n = 0; n < 4; ++n)
                    acc[m][n] = MFMA(af[m], bfr[n], acc[m][n]);
        }
        __syncthreads();
    }

    // epilogue. D layout: col = lane&15, row = (lane>>4)*4 + r  [verified m89/m91]
#pragma unroll
    for (int n = 0; n < 4; ++n) {
        int col = n0 + wc * 64 + n * 16 + l15;
        float bs = bias[col];
        if constexpr (MODE == 0) {
            int sec = col >> 10;          // 0=q 1=k 2=v
            int cc = col & 1023;
            int h = cc >> 6, d = cc & 63;
            if (sec == 2) {
                // V transposed + swizzled: [B,H,D,T], byte addr =
                // base + (t&~63)*2 + ((t&63)*2 ^ ((d&15)<<3)); t 4-aligned
#pragma unroll
                for (int m = 0; m < 4; ++m) {
                    int rowb = m0 + wr * 64 + m * 16 + lg * 4;
                    int bb = rowb >> 11, t = rowb & 2047;
                    bf16x4 pk;
#pragma unroll
                    for (int r = 0; r < 4; ++r) pk[r] = (__bf16)(acc[m][n][r] + bs);
                    size_t base = ((size_t)(bb * NH + h) * HD + d) * (TT * 2);
                    size_t byte = base + (size_t)((t & ~63) * 2 +
                                   (((t & 63) * 2) ^ ((d & 15) << 3)));
                    *(bf16x4*)((char*)ov + byte) = pk;
                }
            } else {
                __bf16* dst = (sec == 0) ? oq : ok;
                // fold softmax scale AND log2(e) into q so attn uses exp2
                float mult = (sec == 0) ? 0.125f * 1.44269504088896340736f : 1.0f;
#pragma unroll
                for (int m = 0; m < 4; ++m) {
                    int rowb = m0 + wr * 64 + m * 16 + lg * 4;
#pragma unroll
                    for (int r = 0; r < 4; ++r) {
                        int row = rowb + r;
                        int bb = row >> 11, t = row & 2047;
                        float val = (acc[m][n][r] + bs) * mult;
                        dst[((size_t)(bb * NH + h) * TT + t) * HD + d] = (__bf16)val;
                    }
                }
            }
        } else {
#pragma unroll
            for (int m = 0; m < 4; ++m) {
                int rowb = m0 + wr * 64 + m * 16 + lg * 4;
#pragma unroll
                for (int r = 0; r < 4; ++r) {
                    int row = rowb + r;
                    of[(size_t)row * N + col] = acc[m][n][r] + bs;
                }
            }
        }
    }
}

// ---------------- causal flash attention (r13 + counted-vmcnt pipeline) --
// One q-tile (64 rows, 4 waves x 16) per block; 1024 blocks; balanced
// mapping {31-a,16+a,15-a,a}: each CU's 4 dispatch rounds sum to 62 steps.
// 4 heads per XCD slot (L2-resident KV). Static softmax (r13): no max
// shift/rescale; masked s=-1e30 -> exp2 -> 0 exactly. P register-resident
// (MFMA16); V b64 reads conflict-free via producer-baked (d&15)<<3 swizzle.
// NEW (r16): 3-buffer K/V + counted s_waitcnt vmcnt(4) + raw s_barrier --
// prefetch distance 2, so no wave ever drains its own fresh prefetch at the
// step barrier (removes the per-step vmcnt(0) drain). 4 loads/wave/stage.
// q,k: [B,H,T,64] bf16 (q pre-scaled by 0.125*log2e). vt: swizzled [B,H,64,T].
__global__ __launch_bounds__(256) void attn_kernel(
    const __bf16* __restrict__ q, const __bf16* __restrict__ k,
    const __bf16* __restrict__ vt, __bf16* __restrict__ y) {
    __shared__ __align__(16) __bf16 Kb[3][64 * 64];   // [kv][d] 128B rows, XOR swz
    __shared__ __align__(16) __bf16 Vb[3][64 * 64];   // [d][kv-swz] 128B rows

    const int n = blockIdx.x;
    const int batch = n >> 8, a = (n >> 5) & 7;
    // balanced coverage: {31-a, 16+a, 15-a, a} sums to 62 for every a
    const int qt = (batch == 0) ? 31 - a : (batch == 1) ? 16 + a
                 : (batch == 2) ? 15 - a : a;
    const int bh = ((n & 7) << 2) | ((n >> 3) & 3);  // 4 heads per XCD slot
    const int tid = threadIdx.x, w = tid >> 6, lane = tid & 63;
    const int l15 = lane & 15, lg = lane >> 4;
    const char* kh = (const char*)(k + (size_t)bh * TT * HD);
    const char* vh = (const char*)(vt + (size_t)bh * HD * TT);
    const __bf16* qh = q + (size_t)bh * TT * HD;
    const int qbw = qt * 64 + w * 16;

    const f32x4 zero4 = {0.f, 0.f, 0.f, 0.f};
    float lrun = 0.f;                  // per-lane partial (16 k each)
    f32x4 oacc[4];                     // O^T: col=q=l15, row d = f*16+lg*4+r
    bf16x8 qf[2];
#pragma unroll
    for (int f = 0; f < 4; ++f) oacc[f] = zero4;
#pragma unroll
    for (int kk = 0; kk < 2; ++kk)
        qf[kk] = *(const bf16x8*)&qh[(size_t)(qbw + l15) * HD + kk * 32 + lg * 8];

    auto stage = [&](int kvb, int buf) {
#pragma unroll
        for (int j = 0; j < 2; ++j) {
            int d0 = ((w * 2 + j) * 64 + lane) * 16;
            int row = d0 >> 7, colb = d0 & 127;
            // K: source-XOR swizzle; V: linear (swizzle baked in global layout)
            gload16(kh + (size_t)(kvb + row) * 128 + (colb ^ ((row & 7) << 4)),
                    (char*)Kb[buf] + d0);
            gload16(vh + (size_t)row * (TT * 2) + (size_t)kvb * 2 + colb,
                    (char*)Vb[buf] + d0);
        }
    };

    // prologue: fill pipeline 2 deep (4 loads/wave per stage)
    stage(0, 0);
    if (qt > 0) {
        stage(64, 1);
        asm volatile("s_waitcnt vmcnt(4)" ::: "memory");  // tile 0 landed
    } else {
        asm volatile("s_waitcnt vmcnt(0)" ::: "memory");
    }
    __builtin_amdgcn_sched_barrier(0);
    __builtin_amdgcn_s_barrier();

    for (int g = 0; g <= qt; ++g) {
        const int cur = g % 3;
        if (g + 2 <= qt) stage((g + 2) * 64, (g + 2) % 3);
        const int kb = g * 64;

        // ---- S^T = K Q^T ---- (col=q=l15, row k = kf*16 + lg*4 + r)
        f32x4 s[4];
#pragma unroll
        for (int kf = 0; kf < 4; ++kf) s[kf] = zero4;
        __builtin_amdgcn_s_setprio(1);
#pragma unroll
        for (int kf = 0; kf < 4; ++kf) {
            int krow = kf * 16 + l15;
            const char* kr = (const char*)Kb[cur] + krow * 128;
            bf16x8 k0 = *(const bf16x8*)(kr + ((lg * 16) ^ ((krow & 7) << 4)));
            bf16x8 k1 = *(const bf16x8*)(kr + ((64 + lg * 16) ^ ((krow & 7) << 4)));
            s[kf] = MFMA(k0, qf[0], s[kf]);
            s[kf] = MFMA(k1, qf[1], s[kf]);
        }
        __builtin_amdgcn_s_setprio(0);
        // only the diagonal tile (g == qt) needs the causal mask
        if (g == qt) {
            const int qq = qbw + l15;
#pragma unroll
            for (int kf = 0; kf < 4; ++kf)
#pragma unroll
                for (int r = 0; r < 4; ++r) {
                    int kk_ = kb + kf * 16 + lg * 4 + r;
                    if (kk_ > qq) s[kf][r] = -1e30f;
                }
        }
        // ---- static softmax: P = exp2(s), no max shift, no rescale ----
        float ss = 0.f;
        sh4 pb[4];                         // P^T bf16, register-resident
#pragma unroll
        for (int kf = 0; kf < 4; ++kf) {
            bf16x4 pk;
#pragma unroll
            for (int r = 0; r < 4; ++r) {
                float p = exp2f(s[kf][r]);   // masked (-1e30) -> 0 exactly
                pk[r] = (__bf16)p;
                ss += p;
            }
            pb[kf] = __builtin_bit_cast(sh4, pk);
        }
        lrun += ss;                        // cross-lane sum deferred to epilogue
        // ---- O^T += V^T P ---- 16x16x16: A=V^T (k=lg*4+j via baked swizzle)
        __builtin_amdgcn_s_setprio(1);
#pragma unroll
        for (int kf = 0; kf < 4; ++kf) {
            int cb = (kf * 32 + lg * 8) ^ (l15 << 3);
#pragma unroll
            for (int f = 0; f < 4; ++f) {
                int vrow = f * 16 + l15;
                bf16x4 va = *(const bf16x4*)((const char*)Vb[cur] + vrow * 128 + cb);
                oacc[f] = MFMA16(__builtin_bit_cast(sh4, va), pb[kf], oacc[f]);
            }
        }
        __builtin_amdgcn_s_setprio(0);

        // counted-vmcnt sync: tile g+1 landed; tile g+2's loads stay in flight
        if (g < qt) {
            if (g + 2 <= qt) asm volatile("s_waitcnt vmcnt(4)" ::: "memory");
            else             asm volatile("s_waitcnt vmcnt(0)" ::: "memory");
            __builtin_amdgcn_sched_barrier(0);
            __builtin_amdgcn_s_barrier();
        }
    }

    // epilogue: finish the lrun reduction across the 4 lg groups, write O^T
    lrun += __shfl_xor(lrun, 16);
    lrun += __shfl_xor(lrun, 32);
    const int b = bh >> 4, h = bh & 15;
    float inv = 1.0f / lrun;
#pragma unroll
    for (int f = 0; f < 4; ++f) {
        bf16x4 pk;
#pragma unroll
        for (int r = 0; r < 4; ++r) pk[r] = (__bf16)(oacc[f][r] * inv);
        *(bf16x4*)&y[(size_t)(b * TT + qbw + l15) * CC + h * 64 + f * 16 +
                     lg * 4] = pk;
    }
}

extern "C" void kernel_launch(void* const* d_in, const int* in_sizes, int n_in,
                              void* d_out, int out_size, void* d_ws, size_t ws_size,
                              hipStream_t stream) {
    const float* x      = (const float*)d_in[0];
    const float* w_attn = (const float*)d_in[1];
    const float* b_attn = (const float*)d_in[2];
    const float* w_proj = (const float*)d_in[3];
    const float* b_proj = (const float*)d_in[4];
    float* out = (float*)d_out;

    char* ws = (char*)d_ws;
    size_t off = 0;
    auto alloc = [&](size_t bytes) {
        char* p = ws + off;
        off += (bytes + 255) & ~(size_t)255;
        return p;
    };
    __bf16* xb   = (__bf16*)alloc((size_t)BT * CC * 2);
    __bf16* watb = (__bf16*)alloc((size_t)3 * CC * CC * 2);
    __bf16* wptb = (__bf16*)alloc((size_t)CC * CC * 2);
    __bf16* qb   = (__bf16*)alloc((size_t)BT * CC * 2);
    __bf16* kbuf = (__bf16*)alloc((size_t)BT * CC * 2);
    __bf16* vtb  = (__bf16*)alloc((size_t)BT * CC * 2);  // [B,H,D,T] swizzled
    __bf16* yb   = (__bf16*)alloc((size_t)BT * CC * 2);

    prep<<<5120, 256, 0, stream>>>(x, xb, w_attn, watb, w_proj, wptb);

    gemm128<0><<<dim3(3 * CC / 128, BT / 128), 256, 0, stream>>>(
        xb, watb, b_attn, qb, kbuf, vtb, nullptr, BT, 3 * CC, CC);

    attn_kernel<<<1024, 256, 0, stream>>>(qb, kbuf, vtb, yb);

    gemm128<1><<<dim3(CC / 128, BT / 128), 256, 0, stream>>>(
        yb, wptb, b_proj, nullptr, nullptr, nullptr, out, BT, CC, CC);
}

// Round 17
// 109.072 us; speedup vs baseline: 1.1807x; 1.0002x over previous
//
#include <hip/hip_runtime.h>
#include <hip/hip_bf16.h>
#include <stdint.h>

// Problem constants: B=2, T=2048, C=1024, H=16, D=64
#define TT 2048
#define CC 1024
#define NH 16
#define HD 64
#define BT 4096          // B*T rows

typedef float f32x4 __attribute__((ext_vector_type(4)));
typedef __bf16 bf16x8 __attribute__((ext_vector_type(8)));
typedef __bf16 bf16x4 __attribute__((ext_vector_type(4)));
typedef short sh4 __attribute__((ext_vector_type(4)));

#define MFMA(a, b, c) __builtin_amdgcn_mfma_f32_16x16x32_bf16((a), (b), (c), 0, 0, 0)
#define MFMA16(a, b, c) __builtin_amdgcn_mfma_f32_16x16x16bf16_1k((a), (b), (c), 0, 0, 0)

__device__ __forceinline__ void gload16(const void* g, void* l) {
    __builtin_amdgcn_global_load_lds(
        (const __attribute__((address_space(1))) void*)g,
        (__attribute__((address_space(3))) void*)l,
        16, 0, 0);
}

// ------- fused prep: x fp32->bf16 convert + both weight transposes -------
__global__ __launch_bounds__(256) void prep(
    const float* __restrict__ x, __bf16* __restrict__ xb,
    const float* __restrict__ wa, __bf16* __restrict__ oa,
    const float* __restrict__ wp, __bf16* __restrict__ op) {
    __shared__ float tile[32][33];
    int b0 = blockIdx.x;
    if (b0 < 1024) {
        // conv: x [BT*CC] fp32 -> bf16
        int i = b0 * 256 + threadIdx.x;
        const int stride = 1024 * 256;
        const int n4 = BT * CC / 4;
        for (; i < n4; i += stride) {
            float4 v = reinterpret_cast<const float4*>(x)[i];
            bf16x4 o;
            o.x = (__bf16)v.x; o.y = (__bf16)v.y;
            o.z = (__bf16)v.z; o.w = (__bf16)v.w;
            reinterpret_cast<bf16x4*>(xb)[i] = o;
        }
    } else {
        // transpose: w_attn [1024][3072] / w_proj [1024][1024] -> bf16 [C][1024]
        int idx = b0 - 1024;
        int bx = idx & 127, r0 = (idx >> 7) * 32;
        const float* in;
        __bf16* out;
        int C;
        if (bx < 96) { in = wa; out = oa; C = 3072; }
        else         { in = wp; out = op; C = 1024; bx -= 96; }
        int c0 = bx * 32;
        int tx = threadIdx.x & 31, ty = (threadIdx.x >> 5) & 7;
#pragma unroll
        for (int j = 0; j < 32; j += 8)
            tile[ty + j][tx] = in[(size_t)(r0 + ty + j) * C + c0 + tx];
        __syncthreads();
#pragma unroll
        for (int j = 0; j < 32; j += 8)
            out[(size_t)(c0 + ty + j) * 1024 + r0 + tx] = (__bf16)tile[tx][ty + j];
    }
}

// ---------------- bf16 MFMA GEMM, 128x128 tile, BK=64 (m97 structure) ----
// C = A[M,K] * Bt[N,K]^T + bias. MODE 0: scatter q/k -> [B,H,T,D] bf16
// (q scaled by 0.125*log2e for exp2-softmax); v -> [B,H,D,T] bf16 with the
// attention V-swizzle PRE-BAKED per 128B (64-kv) group [r10/r11: conflicts=0].
// MODE 1: fp32 out.
// XPX = B-panel columns per XCD. Grid is 1-D; hardware dispatches
// blockIdx round-robin over 8 XCDs (xcd = id&7, measured m09), so id&7
// selects the XCD-local panel group: each XCD keeps its XPX B-panels
// (XPX*256KB) L2-resident, and x-fastest slot ordering makes co-resident
// blocks share one A-panel -> A re-reads served by L2 instead of L3.
template <int MODE, int XPX>
__global__ __launch_bounds__(256) void gemm128(
    const __bf16* __restrict__ A, const __bf16* __restrict__ Bt,
    const float* __restrict__ bias,
    __bf16* __restrict__ oq, __bf16* __restrict__ ok, __bf16* __restrict__ ov,
    float* __restrict__ of, int M, int N, int K) {
    __shared__ __align__(16) __bf16 As[128 * 64];
    __shared__ __align__(16) __bf16 Bs[128 * 64];
    const int tid = threadIdx.x;
    const int w = tid >> 6, lane = tid & 63;
    const int l15 = lane & 15, lg = lane >> 4;
    // XCD-aware remap (bijective): j = xcd, s = per-XCD slot
    const int id = blockIdx.x;
    const int jx = id & 7, s = id >> 3;
    const int xcol = jx * XPX + (s % XPX);
    const int yrow = s / XPX;
    const int m0 = yrow * 128, n0 = xcol * 128;
    const int wr = w >> 1, wc = w & 1;

    const f32x4 zero4 = {0.f, 0.f, 0.f, 0.f};
    f32x4 acc[4][4];
#pragma unroll
    for (int m = 0; m < 4; ++m)
#pragma unroll
        for (int n = 0; n < 4; ++n) acc[m][n] = zero4;

    const char* Ab = (const char*)A;
    const char* Bb = (const char*)Bt;
    const size_t rowbytes = (size_t)K * 2;

    for (int kt = 0; kt < K; kt += 64) {
#pragma unroll
        for (int j = 0; j < 4; ++j) {
            int base = (w * 4 + j) * 1024;
            int d0 = base + lane * 16;
            int row = d0 >> 7;
            int colb = d0 & 127;
            int scolb = colb ^ ((row & 7) << 4);
            gload16(Ab + (size_t)(m0 + row) * rowbytes + (size_t)kt * 2 + scolb,
                    (char*)As + base);
            gload16(Bb + (size_t)(n0 + row) * rowbytes + (size_t)kt * 2 + scolb,
                    (char*)Bs + base);
        }
        __syncthreads();
#pragma unroll
        for (int kk = 0; kk < 2; ++kk) {
            bf16x8 af[4], bfr[4];
#pragma unroll
            for (int m = 0; m < 4; ++m) {
                int row = wr * 64 + m * 16 + l15;
                int colb = kk * 64 + lg * 16;
                af[m] = *(const bf16x8*)((const char*)As + row * 128 +
                                         (colb ^ ((row & 7) << 4)));
            }
#pragma unroll
            for (int n = 0; n < 4; ++n) {
                int row = wc * 64 + n * 16 + l15;
                int colb = kk * 64 + lg * 16;
                bfr[n] = *(const bf16x8*)((const char*)Bs + row * 128 +
                                          (colb ^ ((row & 7) << 4)));
            }
#pragma unroll
            for (int m = 0; m < 4; ++m)
#pragma unroll
                for (int n = 0; n < 4; ++n)
                    acc[m][n] = MFMA(af[m], bfr[n], acc[m][n]);
        }
        __syncthreads();
    }

    // epilogue. D layout: col = lane&15, row = (lane>>4)*4 + r  [verified m89/m91]
#pragma unroll
    for (int n = 0; n < 4; ++n) {
        int col = n0 + wc * 64 + n * 16 + l15;
        float bs = bias[col];
        if constexpr (MODE == 0) {
            int sec = col >> 10;          // 0=q 1=k 2=v
            int cc = col & 1023;
            int h = cc >> 6, d = cc & 63;
            if (sec == 2) {
                // V transposed + swizzled: [B,H,D,T], byte addr =
                // base + (t&~63)*2 + ((t&63)*2 ^ ((d&15)<<3)); t 4-aligned
#pragma unroll
                for (int m = 0; m < 4; ++m) {
                    int rowb = m0 + wr * 64 + m * 16 + lg * 4;
                    int bb = rowb >> 11, t = rowb & 2047;
                    bf16x4 pk;
#pragma unroll
                    for (int r = 0; r < 4; ++r) pk[r] = (__bf16)(acc[m][n][r] + bs);
                    size_t base = ((size_t)(bb * NH + h) * HD + d) * (TT * 2);
                    size_t byte = base + (size_t)((t & ~63) * 2 +
                                   (((t & 63) * 2) ^ ((d & 15) << 3)));
                    *(bf16x4*)((char*)ov + byte) = pk;
                }
            } else {
                __bf16* dst = (sec == 0) ? oq : ok;
                // fold softmax scale AND log2(e) into q so attn uses exp2
                float mult = (sec == 0) ? 0.125f * 1.44269504088896340736f : 1.0f;
#pragma unroll
                for (int m = 0; m < 4; ++m) {
                    int rowb = m0 + wr * 64 + m * 16 + lg * 4;
#pragma unroll
                    for (int r = 0; r < 4; ++r) {
                        int row = rowb + r;
                        int bb = row >> 11, t = row & 2047;
                        float val = (acc[m][n][r] + bs) * mult;
                        dst[((size_t)(bb * NH + h) * TT + t) * HD + d] = (__bf16)val;
                    }
                }
            }
        } else {
#pragma unroll
            for (int m = 0; m < 4; ++m) {
                int rowb = m0 + wr * 64 + m * 16 + lg * 4;
#pragma unroll
                for (int r = 0; r < 4; ++r) {
                    int row = rowb + r;
                    of[(size_t)row * N + col] = acc[m][n][r] + bs;
                }
            }
        }
    }
}

// ---------------- causal flash attention (r13 config — session best) -----
// One q-tile (64 rows, 4 waves x 16) per block; 1024 blocks; balanced
// mapping {31-a,16+a,15-a,a}: each CU slot-group sums to 62 steps. 4 heads
// per XCD slot (L2-resident KV). Static softmax: no max shift/rescale;
// masked s=-1e30 -> exp2 -> 0 exactly. P register-resident (MFMA16);
// V b64 reads conflict-free via producer-baked (d&15)<<3 swizzle. LDS 32KB.
// q,k: [B,H,T,64] bf16 (q pre-scaled by 0.125*log2e). vt: swizzled [B,H,64,T].
__global__ __launch_bounds__(256) void attn_kernel(
    const __bf16* __restrict__ q, const __bf16* __restrict__ k,
    const __bf16* __restrict__ vt, __bf16* __restrict__ y) {
    __shared__ __align__(16) __bf16 Kb[2][64 * 64];   // [kv][d] 128B rows, XOR swz
    __shared__ __align__(16) __bf16 Vb[2][64 * 64];   // [d][kv-swz] 128B rows

    const int n = blockIdx.x;
    const int batch = n >> 8, a = (n >> 5) & 7;
    // balanced coverage: {31-a, 16+a, 15-a, a} sums to 62 for every a
    const int qt = (batch == 0) ? 31 - a : (batch == 1) ? 16 + a
                 : (batch == 2) ? 15 - a : a;
    const int bh = ((n & 7) << 2) | ((n >> 3) & 3);  // 4 heads per XCD slot
    const int tid = threadIdx.x, w = tid >> 6, lane = tid & 63;
    const int l15 = lane & 15, lg = lane >> 4;
    const char* kh = (const char*)(k + (size_t)bh * TT * HD);
    const char* vh = (const char*)(vt + (size_t)bh * HD * TT);
    const __bf16* qh = q + (size_t)bh * TT * HD;
    const int qbw = qt * 64 + w * 16;

    const f32x4 zero4 = {0.f, 0.f, 0.f, 0.f};
    float lrun = 0.f;                  // per-lane partial (16 k each)
    f32x4 oacc[4];                     // O^T: col=q=l15, row d = f*16+lg*4+r
    bf16x8 qf[2];
#pragma unroll
    for (int f = 0; f < 4; ++f) oacc[f] = zero4;
#pragma unroll
    for (int kk = 0; kk < 2; ++kk)
        qf[kk] = *(const bf16x8*)&qh[(size_t)(qbw + l15) * HD + kk * 32 + lg * 8];

    auto stage = [&](int kvb, int buf) {
#pragma unroll
        for (int j = 0; j < 2; ++j) {
            int d0 = ((w * 2 + j) * 64 + lane) * 16;
            int row = d0 >> 7, colb = d0 & 127;
            // K: source-XOR swizzle; V: linear (swizzle baked in global layout)
            gload16(kh + (size_t)(kvb + row) * 128 + (colb ^ ((row & 7) << 4)),
                    (char*)Kb[buf] + d0);
            gload16(vh + (size_t)row * (TT * 2) + (size_t)kvb * 2 + colb,
                    (char*)Vb[buf] + d0);
        }
    };

    stage(0, 0);
    __syncthreads();

    for (int g = 0; g <= qt; ++g) {
        const int cur = g & 1;
        if (g < qt) stage((g + 1) * 64, cur ^ 1);
        const int kb = g * 64;

        // ---- S^T = K Q^T ---- (col=q=l15, row k = kf*16 + lg*4 + r)
        f32x4 s[4];
#pragma unroll
        for (int kf = 0; kf < 4; ++kf) s[kf] = zero4;
        __builtin_amdgcn_s_setprio(1);
#pragma unroll
        for (int kf = 0; kf < 4; ++kf) {
            int krow = kf * 16 + l15;
            const char* kr = (const char*)Kb[cur] + krow * 128;
            bf16x8 k0 = *(const bf16x8*)(kr + ((lg * 16) ^ ((krow & 7) << 4)));
            bf16x8 k1 = *(const bf16x8*)(kr + ((64 + lg * 16) ^ ((krow & 7) << 4)));
            s[kf] = MFMA(k0, qf[0], s[kf]);
            s[kf] = MFMA(k1, qf[1], s[kf]);
        }
        __builtin_amdgcn_s_setprio(0);
        // only the diagonal tile (g == qt) needs the causal mask
        if (g == qt) {
            const int qq = qbw + l15;
#pragma unroll
            for (int kf = 0; kf < 4; ++kf)
#pragma unroll
                for (int r = 0; r < 4; ++r) {
                    int kk_ = kb + kf * 16 + lg * 4 + r;
                    if (kk_ > qq) s[kf][r] = -1e30f;
                }
        }
        // ---- static softmax: P = exp2(s), no max shift, no rescale ----
        float ss = 0.f;
        sh4 pb[4];                         // P^T bf16, register-resident
#pragma unroll
        for (int kf = 0; kf < 4; ++kf) {
            bf16x4 pk;
#pragma unroll
            for (int r = 0; r < 4; ++r) {
                float p = exp2f(s[kf][r]);   // masked (-1e30) -> 0 exactly
                pk[r] = (__bf16)p;
                ss += p;
            }
            pb[kf] = __builtin_bit_cast(sh4, pk);
        }
        lrun += ss;                        // cross-lane sum deferred to epilogue
        // ---- O^T += V^T P ---- 16x16x16: A=V^T (k=lg*4+j via baked swizzle)
        __builtin_amdgcn_s_setprio(1);
#pragma unroll
        for (int kf = 0; kf < 4; ++kf) {
            int cb = (kf * 32 + lg * 8) ^ (l15 << 3);
#pragma unroll
            for (int f = 0; f < 4; ++f) {
                int vrow = f * 16 + l15;
                bf16x4 va = *(const bf16x4*)((const char*)Vb[cur] + vrow * 128 + cb);
                oacc[f] = MFMA16(__builtin_bit_cast(sh4, va), pb[kf], oacc[f]);
            }
        }
        __builtin_amdgcn_s_setprio(0);
        __syncthreads();
    }

    // epilogue: finish the lrun reduction across the 4 lg groups, write O^T
    lrun += __shfl_xor(lrun, 16);
    lrun += __shfl_xor(lrun, 32);
    const int b = bh >> 4, h = bh & 15;
    float inv = 1.0f / lrun;
#pragma unroll
    for (int f = 0; f < 4; ++f) {
        bf16x4 pk;
#pragma unroll
        for (int r = 0; r < 4; ++r) pk[r] = (__bf16)(oacc[f][r] * inv);
        *(bf16x4*)&y[(size_t)(b * TT + qbw + l15) * CC + h * 64 + f * 16 +
                     lg * 4] = pk;
    }
}

extern "C" void kernel_launch(void* const* d_in, const int* in_sizes, int n_in,
                              void* d_out, int out_size, void* d_ws, size_t ws_size,
                              hipStream_t stream) {
    const float* x      = (const float*)d_in[0];
    const float* w_attn = (const float*)d_in[1];
    const float* b_attn = (const float*)d_in[2];
    const float* w_proj = (const float*)d_in[3];
    const float* b_proj = (const float*)d_in[4];
    float* out = (float*)d_out;

    char* ws = (char*)d_ws;
    size_t off = 0;
    auto alloc = [&](size_t bytes) {
        char* p = ws + off;
        off += (bytes + 255) & ~(size_t)255;
        return p;
    };
    __bf16* xb   = (__bf16*)alloc((size_t)BT * CC * 2);
    __bf16* watb = (__bf16*)alloc((size_t)3 * CC * CC * 2);
    __bf16* wptb = (__bf16*)alloc((size_t)CC * CC * 2);
    __bf16* qb   = (__bf16*)alloc((size_t)BT * CC * 2);
    __bf16* kbuf = (__bf16*)alloc((size_t)BT * CC * 2);
    __bf16* vtb  = (__bf16*)alloc((size_t)BT * CC * 2);  // [B,H,D,T] swizzled
    __bf16* yb   = (__bf16*)alloc((size_t)BT * CC * 2);

    prep<<<5120, 256, 0, stream>>>(x, xb, w_attn, watb, w_proj, wptb);

    // gemm0: N=3072 -> 24 B-panel columns, 3 per XCD; 1-D grid 768
    gemm128<0, 3><<<768, 256, 0, stream>>>(
        xb, watb, b_attn, qb, kbuf, vtb, nullptr, BT, 3 * CC, CC);

    attn_kernel<<<1024, 256, 0, stream>>>(qb, kbuf, vtb, yb);

    // gemm1: N=1024 -> 8 B-panel columns, 1 per XCD; 1-D grid 256
    gemm128<1, 1><<<256, 256, 0, stream>>>(
        yb, wptb, b_proj, nullptr, nullptr, nullptr, out, BT, CC, CC);
}